// Round 16
// baseline (21.002 us; speedup 1.0000x reference)
//
#include <hip/hip_runtime.h>

#define N_PTS 4096
#define B_SZ 4
#define C_IN 64
#define C_OUT 128
#define NS 9
#define KTOT (C_IN * NS)   // 576
#define RAD2 0.04f

typedef __attribute__((ext_vector_type(8))) short bf16x8;
typedef __attribute__((ext_vector_type(4))) float f32x4;

__device__ inline ushort f2bf(float f) {
    union { float f; unsigned u; } v; v.f = f;
    unsigned r = (v.u + 0x7FFF + ((v.u >> 16) & 1)) >> 16;   // RTNE
    return (ushort)r;
}

__device__ inline void gl_lds16(const void* g, void* l) {
    __builtin_amdgcn_global_load_lds(
        (const __attribute__((address_space(1))) unsigned int*)g,
        (__attribute__((address_space(3))) unsigned int*)l, 16, 0, 0);
}

// ---- ballq v5: 4 centers/wave share one candidate stream ----
// Candidate index = gi*256 + 4*lane + k (v4's verified order/prefix logic,
// applied per center). sqm computed once per candidate, reused by 4 centers.
#define LOADG4(gi, qx, qy, qz) do {                                         \
    int base_ = (gi) * 256 + 4 * lane;                                      \
    qx = *(const float4*)(pb + base_);                                      \
    qy = *(const float4*)(pb + N_PTS + base_);                              \
    qz = *(const float4*)(pb + 2 * N_PTS + base_);                          \
} while (0)

#define PROCG5(gi, qx, qy, qz) do {                                         \
    const float* fx_ = (const float*)&qx;                                   \
    const float* fy_ = (const float*)&qy;                                   \
    const float* fz_ = (const float*)&qz;                                   \
    float sqm_[4];                                                          \
    _Pragma("unroll")                                                       \
    for (int k_ = 0; k_ < 4; ++k_)                                          \
        sqm_[k_] = __fadd_rn(__fadd_rn(__fmul_rn(fx_[k_], fx_[k_]),         \
                                       __fmul_rn(fy_[k_], fy_[k_])),        \
                             __fmul_rn(fz_[k_], fz_[k_]));                  \
    _Pragma("unroll")                                                       \
    for (int c_ = 0; c_ < 4; ++c_) {                                        \
        if (cnt[c_] < NS) {                                                 \
            unsigned long long mm_[4]; int hit_[4];                         \
            _Pragma("unroll")                                               \
            for (int k_ = 0; k_ < 4; ++k_) {                                \
                float dot_ = __fadd_rn(__fadd_rn(__fmul_rn(cx[c_], fx_[k_]),\
                                                 __fmul_rn(cy[c_], fy_[k_])),\
                                       __fmul_rn(cz[c_], fz_[k_]));         \
                float d2_ = __fsub_rn(__fadd_rn(csq[c_], sqm_[k_]),         \
                                      __fmul_rn(2.0f, dot_));               \
                hit_[k_] = !(d2_ > RAD2);                                   \
                mm_[k_] = __ballot(hit_[k_]);                               \
            }                                                               \
            unsigned long long any_ = mm_[0] | mm_[1] | mm_[2] | mm_[3];    \
            if (any_) {                                                     \
                if (first[c_] < 0) {                                        \
                    int f_ = 0x7fffffff;                                    \
                    _Pragma("unroll")                                       \
                    for (int k_ = 0; k_ < 4; ++k_)                          \
                        if (mm_[k_]) {                                      \
                            int i_ = (gi) * 256 + 4 * (__ffsll(mm_[k_]) - 1) + k_; \
                            f_ = min(f_, i_);                               \
                        }                                                   \
                    first[c_] = f_;                                         \
                }                                                           \
                int p_ = 0;                                                 \
                _Pragma("unroll")                                           \
                for (int k_ = 0; k_ < 4; ++k_)                              \
                    p_ += __builtin_amdgcn_mbcnt_hi((unsigned)(mm_[k_] >> 32), \
                              __builtin_amdgcn_mbcnt_lo((unsigned)mm_[k_], 0)); \
                int own_ = 0;                                               \
                _Pragma("unroll")                                           \
                for (int k_ = 0; k_ < 4; ++k_) {                            \
                    if (hit_[k_]) {                                         \
                        int slot_ = cnt[c_] + p_ + own_;                    \
                        if (slot_ < NS)                                     \
                            outB[(size_t)slot_ * N_PTS + c_] =              \
                                (gi) * 256 + 4 * lane + k_;                 \
                    }                                                       \
                    own_ += hit_[k_];                                       \
                }                                                           \
                cnt[c_] += __popcll(mm_[0]) + __popcll(mm_[1])              \
                         + __popcll(mm_[2]) + __popcll(mm_[3]);             \
            }                                                               \
        }                                                                   \
    }                                                                       \
} while (0)

#define ALLDONE (cnt[0] >= NS && cnt[1] >= NS && cnt[2] >= NS && cnt[3] >= NS)

// ---------------- kernel 0: fused prep (wt | xt | ballq), role by blockIdx ----
// blocks [0,288):       W -> Wt bf16 PRE-SWIZZLED
// blocks [288,544):     x [b][c][n] fp32 -> xT [b][n][c] bf16
// blocks [544,1568):    ball query v5: 16 points/block (4/wave), shared
//                       candidate stream, no barriers
__global__ void __launch_bounds__(256) prep_kernel(
    const float* __restrict__ W, const float* __restrict__ x,
    const float* __restrict__ pcs,
    ushort* __restrict__ Wt, ushort* __restrict__ xT, int* __restrict__ idxT)
{
    __shared__ ushort tile[64][66];
    const int t = threadIdx.x;
    const int blk = blockIdx.x;

    if (blk < 288) {                       // ---- Wt (pre-swizzled) ----
        int id = blk * 256 + t;
        int o = id / KTOT;
        int r = id - o * KTOT;             // s*64 + c
        int s = r >> 6, c = r & 63;
        int dst = o * KTOT + s * 64 + (((c >> 3) ^ (o & 7)) << 3) + (c & 7);
        Wt[dst] = f2bf(W[o * KTOT + c * NS + s]);
    } else if (blk < 544) {                // ---- xT [b][n][c] bf16 ----
        int r = blk - 288;
        int b = r >> 6;
        int n0 = (r & 63) * 64;
        const float* xb = x + (size_t)b * C_IN * N_PTS;
        #pragma unroll
        for (int i = 0; i < 16; ++i) {
            int flat = i * 256 + t;
            int c = flat >> 6, n = flat & 63;
            tile[c][n] = f2bf(xb[(size_t)c * N_PTS + n0 + n]);
        }
        __syncthreads();
        ushort* xTb = xT + ((size_t)b * N_PTS + n0) * C_IN;
        #pragma unroll
        for (int i = 0; i < 16; ++i) {
            int flat = i * 256 + t;
            int n = flat >> 6, c = flat & 63;
            xTb[(size_t)n * C_IN + c] = tile[c][n];
        }
    } else {                               // ---- ball query v5 ----
        const int lane = t & 63;
        const int wid = t >> 6;
        const int nb16 = (blk - 544) * 16 + wid * 4;   // 4 consecutive points
        const int b = nb16 >> 12;                      // blocks never straddle b
        const int n0 = nb16 & (N_PTS - 1);
        const float* pb = pcs + (size_t)b * 3 * N_PTS;

        float cx[4], cy[4], cz[4], csq[4];
        #pragma unroll
        for (int c = 0; c < 4; ++c) {
            int n = n0 + c;
            cx[c] = pb[n]; cy[c] = pb[N_PTS + n]; cz[c] = pb[2 * N_PTS + n];
            csq[c] = __fadd_rn(__fadd_rn(__fmul_rn(cx[c], cx[c]),
                                         __fmul_rn(cy[c], cy[c])),
                               __fmul_rn(cz[c], cz[c]));
        }
        int* outB = idxT + (size_t)b * NS * N_PTS + n0;
        int cnt[4] = {0, 0, 0, 0};
        int first[4] = {-1, -1, -1, -1};

        float4 ax, ay, az, bx, by, bz;
        LOADG4(0, ax, ay, az);
        #pragma unroll 1
        for (int g = 0; g < 16; g += 2) {
            if (g + 1 < 16) LOADG4(g + 1, bx, by, bz);
            PROCG5(g, ax, ay, az);
            if (ALLDONE) break;
            if (g + 2 < 16) LOADG4(g + 2, ax, ay, az);
            PROCG5(g + 1, bx, by, bz);
            if (ALLDONE) break;
        }
        #pragma unroll
        for (int c = 0; c < 4; ++c)
            if (lane >= cnt[c] && lane < NS)
                outB[(size_t)lane * N_PTS + c] = first[c];
    }
}

// ---------------- kernel 1: stage-once MFMA GEMM, 8 waves (r13, proven) ----
__global__ void __launch_bounds__(512) conv_kernel(
    const ushort* __restrict__ xT, const ushort* __restrict__ Wt,
    const int* __restrict__ idxT, const float* __restrict__ bias,
    float* __restrict__ y)
{
    __shared__ __align__(16) ushort Wlds[64 * KTOT];    // 72 KB
    __shared__ __align__(16) ushort Xlds[576 * 64];     // 72 KB

    const int t = threadIdx.x;
    const int lane = t & 63;
    const int wid = t >> 6;          // 0..7
    const int ntile = blockIdx.x;    // 0..63
    const int b = blockIdx.y;        // 0..3
    const int n64 = ntile * 64;
    const int l15 = lane & 15;
    const int l4 = lane >> 4;        // 0..3

    const ushort* xTb = xT + (size_t)b * N_PTS * C_IN;
    const int* idxTb = idxT + (size_t)b * NS * N_PTS;

    const int rb = wid * 72;         // this wave's 72 X rows (row = s*64 + nloc)
    int g[9];
    #pragma unroll
    for (int j = 0; j < 9; ++j) {
        int r = rb + j * 8 + (lane >> 3);
        g[j] = idxTb[((r >> 6) << 12) + n64 + (r & 63)];
    }

    #pragma unroll
    for (int j = 0; j < 9; ++j) {
        int off = (wid * 9 + j) * 512 + lane * 8;
        gl_lds16(Wt + off, &Wlds[off]);
    }
    {
        const int sx = (((lane & 7) ^ (lane >> 3)) << 3);
        #pragma unroll
        for (int j = 0; j < 9; ++j)
            gl_lds16(xTb + ((size_t)g[j] << 6) + sx,
                     &Xlds[(rb + j * 8) * 64 + lane * 8]);
    }
    __syncthreads();   // drains vmcnt (incl. global_load_lds) + barrier

    const int m0 = (wid & 1) * 32;     // wave o-base within 64-half
    const int n0w = (wid >> 1) * 16;   // wave n-base within tile
    const int ra0 = m0 + l15;
    const int rb0 = n0w + l15;
    const int swA = ra0 & 7;
    const int swB = rb0 & 7;
    float* yb = y + (size_t)b * C_OUT * N_PTS + n64;

    #pragma unroll
    for (int half = 0; half < 2; ++half) {
        f32x4 acc[2];
        acc[0] = (f32x4){0.f, 0.f, 0.f, 0.f};
        acc[1] = (f32x4){0.f, 0.f, 0.f, 0.f};

        #pragma unroll
        for (int s = 0; s < NS; ++s) {
            #pragma unroll
            for (int hh = 0; hh < 2; ++hh) {
                int d = hh * 4 + l4;
                bf16x8 a0 = *(const bf16x8*)&Wlds[ra0 * KTOT + s * 64 + ((d ^ swA) << 3)];
                bf16x8 a1 = *(const bf16x8*)&Wlds[(ra0 + 16) * KTOT + s * 64 + ((d ^ swA) << 3)];
                bf16x8 b0 = *(const bf16x8*)&Xlds[(s * 64 + rb0) * 64 + ((d ^ swB) << 3)];
                acc[0] = __builtin_amdgcn_mfma_f32_16x16x32_bf16(a0, b0, acc[0], 0, 0, 0);
                acc[1] = __builtin_amdgcn_mfma_f32_16x16x32_bf16(a1, b0, acc[1], 0, 0, 0);
            }
        }

        // epilogue: C/D col(n)=lane&15, row(o)=l4*4+j
        #pragma unroll
        for (int fm = 0; fm < 2; ++fm) {
            #pragma unroll
            for (int j = 0; j < 4; ++j) {
                int o = half * 64 + m0 + fm * 16 + l4 * 4 + j;
                yb[(size_t)o * N_PTS + n0w + l15] = acc[fm][j] + bias[o];
            }
        }

        if (half == 0) {
            __syncthreads();
            #pragma unroll
            for (int j = 0; j < 9; ++j) {
                int off = (wid * 9 + j) * 512 + lane * 8;
                gl_lds16(Wt + 36864 + off, &Wlds[off]);
            }
            __syncthreads();
        }
    }
}

extern "C" void kernel_launch(void* const* d_in, const int* in_sizes, int n_in,
                              void* d_out, int out_size, void* d_ws, size_t ws_size,
                              hipStream_t stream) {
    const float* x    = (const float*)d_in[0];   // [4,64,4096]
    const float* pcs  = (const float*)d_in[1];   // [4,3,4096]
    const float* W    = (const float*)d_in[2];   // [128,64,9]
    const float* bias = (const float*)d_in[3];   // [128]
    float* y = (float*)d_out;                    // [4,128,4096]

    int*    idxT = (int*)d_ws;                                   // 589824 B
    ushort* xT   = (ushort*)((char*)d_ws + 851968);              // 2097152 B
    ushort* Wt   = (ushort*)((char*)d_ws + 2949120);             // 147456 B

    prep_kernel<<<1568, 256, 0, stream>>>(W, x, pcs, Wt, xT, idxT);
    conv_kernel<<<dim3(64, B_SZ), 512, 0, stream>>>(xT, Wt, idxT, bias, y);
}

// Round 17
// 20.508 us; speedup vs baseline: 1.0241x; 1.0241x over previous
//
#include <hip/hip_runtime.h>

#define N_PTS 4096
#define B_SZ 4
#define C_IN 64
#define C_OUT 128
#define NS 9
#define KTOT (C_IN * NS)   // 576
#define RAD2 0.04f

typedef __attribute__((ext_vector_type(8))) short bf16x8;
typedef __attribute__((ext_vector_type(4))) float f32x4;

__device__ inline ushort f2bf(float f) {
    union { float f; unsigned u; } v; v.f = f;
    unsigned r = (v.u + 0x7FFF + ((v.u >> 16) & 1)) >> 16;   // RTNE
    return (ushort)r;
}

__device__ inline void gl_lds16(const void* g, void* l) {
    __builtin_amdgcn_global_load_lds(
        (const __attribute__((address_space(1))) unsigned int*)g,
        (__attribute__((address_space(3))) unsigned int*)l, 16, 0, 0);
}

// ---- ballq v2 macros: 4-chunk (256-candidate) group, software-pipelined ----
#define LOADG(gi, qx, qy, qz) do {                                          \
    int mbase_ = (gi) * 256 + lane;                                         \
    _Pragma("unroll")                                                       \
    for (int j_ = 0; j_ < 4; ++j_) {                                        \
        int m_ = mbase_ + j_ * 64;                                          \
        qx[j_] = pb[m_]; qy[j_] = pb[N_PTS + m_]; qz[j_] = pb[2 * N_PTS + m_]; \
    }                                                                       \
} while (0)

#define PROCG(gi, qx, qy, qz) do {                                          \
    _Pragma("unroll")                                                       \
    for (int j_ = 0; j_ < 4; ++j_) {                                        \
        int m_ = (gi) * 256 + j_ * 64 + lane;                               \
        float sqm_ = __fadd_rn(__fadd_rn(__fmul_rn(qx[j_], qx[j_]),         \
                                         __fmul_rn(qy[j_], qy[j_])),        \
                               __fmul_rn(qz[j_], qz[j_]));                  \
        float dot_ = __fadd_rn(__fadd_rn(__fmul_rn(cx, qx[j_]),             \
                                         __fmul_rn(cy, qy[j_])),            \
                               __fmul_rn(cz, qz[j_]));                      \
        float d2_ = __fsub_rn(__fadd_rn(csq, sqm_), __fmul_rn(2.0f, dot_)); \
        bool hit_ = !(d2_ > RAD2);                                          \
        unsigned long long mask_ = __ballot(hit_);                          \
        if (mask_) {                                                        \
            if (first < 0) first = (gi) * 256 + j_ * 64 + __ffsll(mask_) - 1; \
            unsigned mlo_ = (unsigned)mask_, mhi_ = (unsigned)(mask_ >> 32); \
            int pre_ = __builtin_amdgcn_mbcnt_hi(mhi_,                      \
                           __builtin_amdgcn_mbcnt_lo(mlo_, 0));             \
            if (hit_) {                                                     \
                int slot_ = cnt + pre_;                                     \
                if (slot_ < NS) outb[(size_t)slot_ * N_PTS] = m_;           \
            }                                                               \
            cnt += __popcll(mask_);                                         \
        }                                                                   \
    }                                                                       \
} while (0)

// ---------------- kernel 0: fused prep (ballq | wt | xt), role by blockIdx ----
// blocks [0,4096):      ball query v2 (long pole, dispatched first)
// blocks [4096,4384):   W -> Wt bf16 PRE-SWIZZLED
// blocks [4384,4640):   x [b][c][n] fp32 -> xT [b][n][c] bf16
__global__ void __launch_bounds__(256) prep_kernel(
    const float* __restrict__ W, const float* __restrict__ x,
    const float* __restrict__ pcs,
    ushort* __restrict__ Wt, ushort* __restrict__ xT, int* __restrict__ idxT)
{
    __shared__ ushort tile[64][66];
    const int t = threadIdx.x;
    const int blk = blockIdx.x;

    if (blk < 4096) {                      // ---- ball query (v2, pipelined) ----
        const int lane = t & 63;
        const int pt = t >> 6;
        const int widp = blk * 4 + pt;     // blocks never straddle b
        const int b = widp >> 12;
        const int n = widp & (N_PTS - 1);
        const float* pb = pcs + (size_t)b * 3 * N_PTS;
        float cx = pb[n], cy = pb[N_PTS + n], cz = pb[2 * N_PTS + n];
        float csq = __fadd_rn(__fadd_rn(__fmul_rn(cx, cx), __fmul_rn(cy, cy)),
                              __fmul_rn(cz, cz));
        int* outb = idxT + (size_t)b * NS * N_PTS + n;
        int cnt = 0, first = -1;
        float ax[4], ay[4], az[4], bx[4], by[4], bz[4];
        LOADG(0, ax, ay, az);
        #pragma unroll 1
        for (int g = 0; g < 16; g += 2) {
            if (g + 1 < 16) LOADG(g + 1, bx, by, bz);
            PROCG(g, ax, ay, az);
            if (cnt >= NS) break;
            if (g + 2 < 16) LOADG(g + 2, ax, ay, az);
            PROCG(g + 1, bx, by, bz);
            if (cnt >= NS) break;
        }
        if (lane >= cnt && lane < NS) outb[(size_t)lane * N_PTS] = first;
    } else if (blk < 4384) {               // ---- Wt (pre-swizzled) ----
        int id = (blk - 4096) * 256 + t;
        int o = id / KTOT;
        int r = id - o * KTOT;             // s*64 + c
        int s = r >> 6, c = r & 63;
        int dst = o * KTOT + s * 64 + (((c >> 3) ^ (o & 7)) << 3) + (c & 7);
        Wt[dst] = f2bf(W[o * KTOT + c * NS + s]);
    } else {                               // ---- xT [b][n][c] bf16 ----
        int r = blk - 4384;
        int b = r >> 6;
        int n0 = (r & 63) * 64;
        const float* xb = x + (size_t)b * C_IN * N_PTS;
        #pragma unroll
        for (int i = 0; i < 16; ++i) {
            int flat = i * 256 + t;
            int c = flat >> 6, n = flat & 63;
            tile[c][n] = f2bf(xb[(size_t)c * N_PTS + n0 + n]);
        }
        __syncthreads();
        ushort* xTb = xT + ((size_t)b * N_PTS + n0) * C_IN;
        #pragma unroll
        for (int i = 0; i < 16; ++i) {
            int flat = i * 256 + t;
            int n = flat >> 6, c = flat & 63;
            xTb[(size_t)n * C_IN + c] = tile[c][n];
        }
    }
}

// ---------------- kernel 1: stage-once MFMA GEMM, 8 waves (r13, proven best) ----
__global__ void __launch_bounds__(512) conv_kernel(
    const ushort* __restrict__ xT, const ushort* __restrict__ Wt,
    const int* __restrict__ idxT, const float* __restrict__ bias,
    float* __restrict__ y)
{
    __shared__ __align__(16) ushort Wlds[64 * KTOT];    // 72 KB
    __shared__ __align__(16) ushort Xlds[576 * 64];     // 72 KB

    const int t = threadIdx.x;
    const int lane = t & 63;
    const int wid = t >> 6;          // 0..7
    const int ntile = blockIdx.x;    // 0..63
    const int b = blockIdx.y;        // 0..3
    const int n64 = ntile * 64;
    const int l15 = lane & 15;
    const int l4 = lane >> 4;        // 0..3

    const ushort* xTb = xT + (size_t)b * N_PTS * C_IN;
    const int* idxTb = idxT + (size_t)b * NS * N_PTS;

    const int rb = wid * 72;         // this wave's 72 X rows (row = s*64 + nloc)
    int g[9];
    #pragma unroll
    for (int j = 0; j < 9; ++j) {
        int r = rb + j * 8 + (lane >> 3);
        g[j] = idxTb[((r >> 6) << 12) + n64 + (r & 63)];
    }

    #pragma unroll
    for (int j = 0; j < 9; ++j) {
        int off = (wid * 9 + j) * 512 + lane * 8;
        gl_lds16(Wt + off, &Wlds[off]);
    }
    {
        const int sx = (((lane & 7) ^ (lane >> 3)) << 3);
        #pragma unroll
        for (int j = 0; j < 9; ++j)
            gl_lds16(xTb + ((size_t)g[j] << 6) + sx,
                     &Xlds[(rb + j * 8) * 64 + lane * 8]);
    }
    __syncthreads();   // drains vmcnt (incl. global_load_lds) + barrier

    const int m0 = (wid & 1) * 32;     // wave o-base within 64-half
    const int n0w = (wid >> 1) * 16;   // wave n-base within tile
    const int ra0 = m0 + l15;
    const int rb0 = n0w + l15;
    const int swA = ra0 & 7;
    const int swB = rb0 & 7;
    float* yb = y + (size_t)b * C_OUT * N_PTS + n64;

    #pragma unroll
    for (int half = 0; half < 2; ++half) {
        f32x4 acc[2];
        acc[0] = (f32x4){0.f, 0.f, 0.f, 0.f};
        acc[1] = (f32x4){0.f, 0.f, 0.f, 0.f};

        #pragma unroll
        for (int s = 0; s < NS; ++s) {
            #pragma unroll
            for (int hh = 0; hh < 2; ++hh) {
                int d = hh * 4 + l4;
                bf16x8 a0 = *(const bf16x8*)&Wlds[ra0 * KTOT + s * 64 + ((d ^ swA) << 3)];
                bf16x8 a1 = *(const bf16x8*)&Wlds[(ra0 + 16) * KTOT + s * 64 + ((d ^ swA) << 3)];
                bf16x8 b0 = *(const bf16x8*)&Xlds[(s * 64 + rb0) * 64 + ((d ^ swB) << 3)];
                acc[0] = __builtin_amdgcn_mfma_f32_16x16x32_bf16(a0, b0, acc[0], 0, 0, 0);
                acc[1] = __builtin_amdgcn_mfma_f32_16x16x32_bf16(a1, b0, acc[1], 0, 0, 0);
            }
        }

        // epilogue: C/D col(n)=lane&15, row(o)=l4*4+j
        #pragma unroll
        for (int fm = 0; fm < 2; ++fm) {
            #pragma unroll
            for (int j = 0; j < 4; ++j) {
                int o = half * 64 + m0 + fm * 16 + l4 * 4 + j;
                yb[(size_t)o * N_PTS + n0w + l15] = acc[fm][j] + bias[o];
            }
        }

        if (half == 0) {
            __syncthreads();
            #pragma unroll
            for (int j = 0; j < 9; ++j) {
                int off = (wid * 9 + j) * 512 + lane * 8;
                gl_lds16(Wt + 36864 + off, &Wlds[off]);
            }
            __syncthreads();
        }
    }
}

extern "C" void kernel_launch(void* const* d_in, const int* in_sizes, int n_in,
                              void* d_out, int out_size, void* d_ws, size_t ws_size,
                              hipStream_t stream) {
    const float* x    = (const float*)d_in[0];   // [4,64,4096]
    const float* pcs  = (const float*)d_in[1];   // [4,3,4096]
    const float* W    = (const float*)d_in[2];   // [128,64,9]
    const float* bias = (const float*)d_in[3];   // [128]
    float* y = (float*)d_out;                    // [4,128,4096]

    int*    idxT = (int*)d_ws;                                   // 589824 B
    ushort* xT   = (ushort*)((char*)d_ws + 851968);              // 2097152 B
    ushort* Wt   = (ushort*)((char*)d_ws + 2949120);             // 147456 B

    prep_kernel<<<4640, 256, 0, stream>>>(W, x, pcs, Wt, xT, idxT);
    conv_kernel<<<dim3(64, B_SZ), 512, 0, stream>>>(xT, Wt, idxT, bias, y);
}